// Round 7
// baseline (479.212 us; speedup 1.0000x reference)
//
#include <hip/hip_runtime.h>

#define CUTOFF_F   0.1f
#define PRESSURE_F 10.0f

// Native clang vector type: __builtin_nontemporal_load requires a pointer to
// scalar/native-vector (HIP_vector_type<float,4> is a struct and is rejected).
typedef float f32x4 __attribute__((ext_vector_type(4)));

// Geometry: one row (256 fp32 = 1 KiB) = one wave (64 lanes x 16B).
// Perfectly coalesced 16 B/lane, 1 KiB per load instruction per array.
// 6-step __shfl_xor butterfly broadcasts the row's sum of squared diffs to
// all 64 lanes -> sqrt + branchless penalty computed wave-uniformly, and the
// per-wave accumulator is lane-uniform (no end-of-loop wave reduce needed).
// Unroll x4 rows: 8 independent global_load_dwordx4 (nt) in flight per
// iteration to hide ~900-cycle HBM latency.
__global__ __launch_bounds__(256) void eucl_loss_kernel(
    const float* __restrict__ a,
    const float* __restrict__ b,
    float* __restrict__ out,
    int nRows,
    float invB)
{
    __shared__ float wave_sums[4];

    const int lane   = threadIdx.x & 63;
    const int wave   = threadIdx.x >> 6;
    const int gwave  = blockIdx.x * 4 + wave;
    const int nwaves = gridDim.x * 4;          // 8192 at grid=2048

    const unsigned lane_e = (unsigned)lane * 4;  // element offset within row

    float acc = 0.0f;   // lane-uniform (butterfly broadcasts row sums)

    for (int r0 = gwave; r0 < nRows; r0 += 4 * nwaves) {
        const int r1 = r0 + nwaves;
        const int r2 = r0 + 2 * nwaves;
        const int r3 = r0 + 3 * nwaves;
        const bool h1 = (r1 < nRows);   // wave-uniform guards (always true at
        const bool h2 = (r2 < nRows);   // B=262144, grid=2048 — kept for safety)
        const bool h3 = (r3 < nRows);

        // Issue all loads first: up to 8 independent vmem ops in flight.
        const f32x4 va0 = __builtin_nontemporal_load(
            reinterpret_cast<const f32x4*>(a + (unsigned)r0 * 256u + lane_e));
        const f32x4 vb0 = __builtin_nontemporal_load(
            reinterpret_cast<const f32x4*>(b + (unsigned)r0 * 256u + lane_e));
        f32x4 va1, vb1, va2, vb2, va3, vb3;
        if (h1) {
            va1 = __builtin_nontemporal_load(
                reinterpret_cast<const f32x4*>(a + (unsigned)r1 * 256u + lane_e));
            vb1 = __builtin_nontemporal_load(
                reinterpret_cast<const f32x4*>(b + (unsigned)r1 * 256u + lane_e));
        }
        if (h2) {
            va2 = __builtin_nontemporal_load(
                reinterpret_cast<const f32x4*>(a + (unsigned)r2 * 256u + lane_e));
            vb2 = __builtin_nontemporal_load(
                reinterpret_cast<const f32x4*>(b + (unsigned)r2 * 256u + lane_e));
        }
        if (h3) {
            va3 = __builtin_nontemporal_load(
                reinterpret_cast<const f32x4*>(a + (unsigned)r3 * 256u + lane_e));
            vb3 = __builtin_nontemporal_load(
                reinterpret_cast<const f32x4*>(b + (unsigned)r3 * 256u + lane_e));
        }

#define ROW_PENALTY(VA, VB)                                                  \
        {                                                                    \
            const float dx = (VA).x - (VB).x;                                \
            const float dy = (VA).y - (VB).y;                                \
            const float dz = (VA).z - (VB).z;                                \
            const float dw = (VA).w - (VB).w;                                \
            float s = dx * dx + dy * dy + dz * dz + dw * dw;                 \
            s += __shfl_xor(s, 32, 64);                                      \
            s += __shfl_xor(s, 16, 64);                                      \
            s += __shfl_xor(s, 8, 64);                                       \
            s += __shfl_xor(s, 4, 64);                                       \
            s += __shfl_xor(s, 2, 64);                                       \
            s += __shfl_xor(s, 1, 64);                                       \
            const float dev = sqrtf(s) - CUTOFF_F;                           \
            const float m   = (dev > 0.0f) ? 1.0f : PRESSURE_F;              \
            acc += dev * dev * m;                                            \
        }

        ROW_PENALTY(va0, vb0)
        if (h1) ROW_PENALTY(va1, vb1)
        if (h2) ROW_PENALTY(va2, vb2)
        if (h3) ROW_PENALTY(va3, vb3)
#undef ROW_PENALTY
    }

    // acc is identical across the wave's lanes; lane 0 publishes it.
    if (lane == 0) wave_sums[wave] = acc;
    __syncthreads();

    if (threadIdx.x == 0) {
        const float t = (wave_sums[0] + wave_sums[1]) + (wave_sums[2] + wave_sums[3]);
        atomicAdd(out, t * invB);
    }
}

extern "C" void kernel_launch(void* const* d_in, const int* in_sizes, int n_in,
                              void* d_out, int out_size, void* d_ws, size_t ws_size,
                              hipStream_t stream) {
    const float* a = (const float*)d_in[0];
    const float* b = (const float*)d_in[1];
    float* out = (float*)d_out;

    const int D = 256;
    const int B = in_sizes[0] / D;        // 262144 rows

    // d_out is re-poisoned to 0xAA before every timed call — zero it async
    // (graph-capture legal).
    (void)hipMemsetAsync(out, 0, sizeof(float), stream);

    const int block = 256;                // 4 waves
    const int grid  = 2048;               // 8 blocks/CU x 256 CU -> 32 waves/CU
    eucl_loss_kernel<<<grid, block, 0, stream>>>(a, b, out, B, 1.0f / (float)B);
}